// Round 1
// baseline (131.399 us; speedup 1.0000x reference)
//
#include <hip/hip_runtime.h>

typedef _Float16 f16;
typedef _Float16 f16x8 __attribute__((ext_vector_type(8)));
typedef float f32x4 __attribute__((ext_vector_type(4)));

#define LOG2E 1.44269504088896f
#define MFMA16(a, b, c) __builtin_amdgcn_mfma_f32_16x16x32_f16(a, b, c, 0, 0, 0)

static __device__ inline f16x8 f16x8_zero() {
    f16x8 v;
#pragma unroll
    for (int i = 0; i < 8; ++i) v[i] = (f16)0.f;
    return v;
}

// ---------------- Kernel 1: projections ----------------
// x: [B,4096,64] f32.  Outputs: fO [B*4096][8] f16, gO [B*4096][8] f16 (pre-scaled by log2e),
// hT [B][64][4096] f16 (transposed so PV MFMA reads contiguous keys).
__global__ __launch_bounds__(256) void proj_kernel(
    const float* __restrict__ x, const float* __restrict__ Kf,
    const float* __restrict__ Kg, const float* __restrict__ Kh,
    const float* __restrict__ bf, const float* __restrict__ bg,
    const float* __restrict__ bh,
    f16* __restrict__ fO, f16* __restrict__ gO, f16* __restrict__ hT)
{
    __shared__ float KT[80 * 64];   // KT[c][d]: c<8 -> f, 8..15 -> g (scaled), 16..79 -> h
    __shared__ float bias[80];
    const int tid = threadIdx.x;

    for (int i = tid; i < 512; i += 256) {          // Kf/Kg are [64][8]
        int d = i >> 3, j = i & 7;
        KT[j * 64 + d] = Kf[i];
        KT[(8 + j) * 64 + d] = Kg[i] * LOG2E;
    }
    for (int i = tid; i < 4096; i += 256) {         // Kh is [64][64]
        int d = i >> 6, c = i & 63;
        KT[(16 + c) * 64 + d] = Kh[i];
    }
    if (tid < 8) { bias[tid] = bf[tid]; bias[8 + tid] = bg[tid] * LOG2E; }
    if (tid >= 16 && tid < 80) bias[tid] = bh[tid - 16];
    __syncthreads();

    const int quarter = tid >> 6;                   // wave id: which 20 output channels
    const int px = blockIdx.x * 64 + (tid & 63);    // pixel (b*4096 + n)
    const float4* xp = (const float4*)(x + (size_t)px * 64);
    float4 xr[16];
#pragma unroll
    for (int i = 0; i < 16; ++i) xr[i] = xp[i];

    float res[20];
    const int c0 = quarter * 20;
#pragma unroll
    for (int cc = 0; cc < 20; ++cc) {
        const int c = c0 + cc;
        float acc = bias[c];
        const float4* wv = (const float4*)(KT + c * 64);
#pragma unroll
        for (int i = 0; i < 16; ++i) {
            float4 w = wv[i];
            acc = fmaf(xr[i].x, w.x, acc);
            acc = fmaf(xr[i].y, w.y, acc);
            acc = fmaf(xr[i].z, w.z, acc);
            acc = fmaf(xr[i].w, w.w, acc);
        }
        res[cc] = acc;
    }

    const int b = px >> 12, n = px & 4095;
    if (quarter == 0) {
        f16x8 fv, gv;
#pragma unroll
        for (int j = 0; j < 8; ++j) { fv[j] = (f16)res[j]; gv[j] = (f16)res[8 + j]; }
        *(f16x8*)(fO + (size_t)px * 8) = fv;
        *(f16x8*)(gO + (size_t)px * 8) = gv;
#pragma unroll
        for (int cc = 16; cc < 20; ++cc)
            hT[(size_t)b * 262144 + (size_t)(cc - 16) * 4096 + n] = (f16)res[cc];
    } else {
#pragma unroll
        for (int cc = 0; cc < 20; ++cc)
            hT[(size_t)b * 262144 + (size_t)(c0 + cc - 16) * 4096 + n] = (f16)res[cc];
    }
}

// ---------------- Kernel 2: flash attention ----------------
// Per block: batch b = blockIdx%8 (matches XCD round-robin), 64 query rows, 4 waves x 16 rows.
// Swapped QK^T (S^T = F * G^T) so q = lane&15 everywhere; PV computes O^T = H^T * P^T.
__global__ __launch_bounds__(256) void attn_kernel(
    const f16* __restrict__ fO, const f16* __restrict__ gO,
    const f16* __restrict__ hT, const float* __restrict__ x,
    const float* __restrict__ gamma, float* __restrict__ out)
{
    __shared__ __align__(16) f16 hbuf[2][64 * 32];       // h^T tile [64 cols][32 keys]
    __shared__ __align__(16) f16 fbuf[2][32 * 8];        // f tile  [32 keys][8 d]
    __shared__ __align__(16) unsigned int pbuf[4][16 * 20]; // per-wave p transpose, stride 20 dw

    const int tid  = threadIdx.x;
    const int w    = tid >> 6;
    const int lane = tid & 63;
    const int lrow = lane & 15;
    const int grp  = lane >> 4;

    const int b     = blockIdx.x & 7;
    const int qt    = blockIdx.x >> 3;
    const int qbase = qt * 64;

    const f16* fb = fO + (size_t)b * 4096 * 8;
    const f16* gb = gO + (size_t)b * 4096 * 8;
    const f16* hb = hT + (size_t)b * 262144;

    // g fragment (B operand of QK): lanes<16 hold g[q][0..7], rest zero (K padded 8->32)
    f16x8 gfrag = f16x8_zero();
    if (lane < 16)
        gfrag = *(const f16x8*)(gb + (size_t)(qbase + w * 16 + lrow) * 8);

    f32x4 acc[4];
#pragma unroll
    for (int cb = 0; cb < 4; ++cb)
#pragma unroll
        for (int r = 0; r < 4; ++r) acc[cb][r] = 0.f;

    float mrun = -1e30f, lpart = 0.f;

    const int col = tid >> 2, ch = tid & 3;   // staging roles: 256 threads cover 64x32 f16 tile

    // prologue: stage tile 0
    {
        uint4 hv = *(const uint4*)(hb + (size_t)col * 4096 + ch * 8);
        *(uint4*)&hbuf[0][tid * 8] = hv;
        if (tid < 32) {
            uint4 fv = *(const uint4*)(fb + (size_t)tid * 8);
            *(uint4*)&fbuf[0][tid * 8] = fv;
        }
    }
    __syncthreads();

    for (int t = 0; t < 128; ++t) {
        const int cur = t & 1;
        const bool pre = (t + 1) < 128;
        uint4 hv, fv;
        if (pre) {                              // issue next-tile global loads early (T14)
            const int k0n = (t + 1) * 32;
            hv = *(const uint4*)(hb + (size_t)col * 4096 + k0n + ch * 8);
            if (tid < 32) fv = *(const uint4*)(fb + (size_t)(k0n + tid) * 8);
        }

        // ---- QK^T (swapped): S^T[key][q] ----
        f16x8 fa0 = f16x8_zero(), fa1 = f16x8_zero();
        if (lane < 16) {
            fa0 = *(const f16x8*)&fbuf[cur][lrow * 8];
            fa1 = *(const f16x8*)&fbuf[cur][(16 + lrow) * 8];
        }
        f32x4 zc;
        zc[0] = zc[1] = zc[2] = zc[3] = 0.f;
        f32x4 s0 = MFMA16(fa0, gfrag, zc);      // keys grp*4+r      , q = lrow
        f32x4 s1 = MFMA16(fa1, gfrag, zc);      // keys 16+grp*4+r   , q = lrow

        // ---- online softmax (logits already in log2 units) ----
        float m8 = fmaxf(fmaxf(fmaxf(s0[0], s0[1]), fmaxf(s0[2], s0[3])),
                         fmaxf(fmaxf(s1[0], s1[1]), fmaxf(s1[2], s1[3])));
        m8 = fmaxf(m8, __shfl_xor(m8, 16));
        m8 = fmaxf(m8, __shfl_xor(m8, 32));
        const float mnew = fmaxf(mrun, m8);
        const float sc = exp2f(mrun - mnew);
        mrun = mnew;
        const float p0 = exp2f(s0[0] - mnew), p1 = exp2f(s0[1] - mnew);
        const float p2 = exp2f(s0[2] - mnew), p3 = exp2f(s0[3] - mnew);
        const float p4 = exp2f(s1[0] - mnew), p5 = exp2f(s1[1] - mnew);
        const float p6 = exp2f(s1[2] - mnew), p7 = exp2f(s1[3] - mnew);
        lpart = lpart * sc + (((p0 + p1) + (p2 + p3)) + ((p4 + p5) + (p6 + p7)));

        // ---- pack p -> f16, transpose via per-wave LDS (write (q,4-key), read (q,8-key)) ----
        auto w0 = __builtin_amdgcn_cvt_pkrtz(p0, p1);
        auto w1 = __builtin_amdgcn_cvt_pkrtz(p2, p3);
        auto w2 = __builtin_amdgcn_cvt_pkrtz(p4, p5);
        auto w3 = __builtin_amdgcn_cvt_pkrtz(p6, p7);
        unsigned int* pw = &pbuf[w][lrow * 20 + 2 * grp];
        uint2 lo, hi;
        lo.x = __builtin_bit_cast(unsigned int, w0);
        lo.y = __builtin_bit_cast(unsigned int, w1);
        hi.x = __builtin_bit_cast(unsigned int, w2);
        hi.y = __builtin_bit_cast(unsigned int, w3);
        *(uint2*)&pw[0] = lo;                    // keys 4g..4g+3
        *(uint2*)&pw[8] = hi;                    // keys 16+4g..16+4g+3
        f16x8 pfrag = *(const f16x8*)((const f16*)&pbuf[w][0] + lrow * 40 + grp * 8);

        // ---- rescale O accumulator (scale is lane-local: O^T col = q = lane&15) ----
#pragma unroll
        for (int cb = 0; cb < 4; ++cb)
#pragma unroll
            for (int r = 0; r < 4; ++r) acc[cb][r] *= sc;

        // ---- PV: O^T[c][q] += H^T[c][k] * P^T[k][q] ----
#pragma unroll
        for (int cb = 0; cb < 4; ++cb) {
            f16x8 ha = *(const f16x8*)&hbuf[cur][(cb * 16 + lrow) * 32 + grp * 8];
            acc[cb] = MFMA16(ha, pfrag, acc[cb]);
        }

        // ---- write staged tile into the other buffer ----
        if (pre) {
            *(uint4*)&hbuf[1 - cur][tid * 8] = hv;
            if (tid < 32) *(uint4*)&fbuf[1 - cur][tid * 8] = fv;
        }
        __syncthreads();
    }

    // ---- epilogue ----
    float lsum = lpart;
    lsum += __shfl_xor(lsum, 16);
    lsum += __shfl_xor(lsum, 32);
    const float rin = 1.0f / lsum;
    const float gm = gamma[0];
    const int qg = (b << 12) + qbase + w * 16 + lrow;
#pragma unroll
    for (int cb = 0; cb < 4; ++cb)
#pragma unroll
        for (int r = 0; r < 4; ++r) {
            const int c = cb * 16 + grp * 4 + r;
            out[(size_t)qg * 64 + c] = fmaf(gm, acc[cb][r] * rin, x[(size_t)qg * 64 + c]);
        }
}

extern "C" void kernel_launch(void* const* d_in, const int* in_sizes, int n_in,
                              void* d_out, int out_size, void* d_ws, size_t ws_size,
                              hipStream_t stream) {
    const float* x     = (const float*)d_in[0];
    const float* Kf    = (const float*)d_in[1];
    const float* Kg    = (const float*)d_in[2];
    const float* Kh    = (const float*)d_in[3];
    const float* bf    = (const float*)d_in[4];
    const float* bg    = (const float*)d_in[5];
    const float* bh    = (const float*)d_in[6];
    const float* gamma = (const float*)d_in[7];
    float* out = (float*)d_out;

    f16* fO = (f16*)d_ws;                               // 512 KB
    f16* gO = (f16*)((char*)d_ws + (512 << 10));        // 512 KB
    f16* hT = (f16*)((char*)d_ws + (1 << 20));          // 4 MB

    hipLaunchKernelGGL(proj_kernel, dim3(512), dim3(256), 0, stream,
                       x, Kf, Kg, Kh, bf, bg, bh, fO, gO, hT);
    hipLaunchKernelGGL(attn_kernel, dim3(512), dim3(256), 0, stream,
                       fO, gO, hT, x, gamma, out);
}